// Round 8
// baseline (4841.005 us; speedup 1.0000x reference)
//
#include <hip/hip_runtime.h>
#include <math.h>

#define BH 256
#define BW 256
#define NB 32
#define NC 32
#define NBLK 1024   // fused-path blocks (4/CU at 256 thr)
#define TPB 256
#define RB 64       // fallback-path reduction blocks per batch

typedef float nfloat4 __attribute__((ext_vector_type(4)));
#define AGENT __HIP_MEMORY_SCOPE_AGENT

// ============================ fused pipelined kernel =========================
// iteration b: reduce slice of batch b; rotate slice of batch b-2 (whose data
// this block streamed through L3 two iterations (~48 MB of traffic) ago ->
// L3-hit gathers). Launched ONLY via hipLaunchCooperativeKernel (co-residency
// guaranteed or the launch errors out and we take the classic path).
__global__ __launch_bounds__(TPB, 4) void k_fused(
    const float* __restrict__ x, const float* __restrict__ Wm,
    const float* __restrict__ bias, float* __restrict__ out,
    float* __restrict__ partial,          // [NB][NBLK]
    unsigned* __restrict__ cnt,           // [NB]
    unsigned* __restrict__ ready,         // [NB]
    float* __restrict__ params)           // [NB][4] = cc, sn, xoff, yoff
{
    const int k = blockIdx.x, t = threadIdx.x;
    const int lane = t & 63, wv = t >> 6;
    __shared__ float red[2][4];           // double-buffered by batch parity

    const int cb = (t * 4) & (NC - 1);    // k*2048 % 32 == 0 -> depends on t only
    const float w0 = Wm[cb], w1 = Wm[cb + 1], w2 = Wm[cb + 2], w3 = Wm[cb + 3];
    const float bias0 = bias[0];

    auto rotate_share = [&](int bb) {
        while (__hip_atomic_load(&ready[bb], __ATOMIC_ACQUIRE, AGENT) == 0u)
            __builtin_amdgcn_s_sleep(1);
        const float cc  = params[bb * 4 + 0];
        const float sn  = params[bb * 4 + 1];
        const float xof = params[bb * 4 + 2];
        const float yof = params[bb * 4 + 3];
        const float* xb = x + (size_t)bb * (BH * BW * NC);
        float* ob = out + (size_t)bb * (BH * BW * NC);
        #pragma unroll
        for (int h = 0; h < 2; ++h) {
            const int j   = k * 512 + h * 256 + t;   // float4 index within batch
            const int c4  = (j & 7) * 4;
            const int pid = j >> 3;
            const int xo = pid & 255, yo = pid >> 8;
            const float fx = (float)xo, fy = (float)yo;
            const float in_x = cc * fx - sn * fy + xof;
            const float in_y = sn * fx + cc * fy + yof;
            const float x0 = floorf(in_x), y0 = floorf(in_y);
            const float wxf = in_x - x0, wyf = in_y - y0;
            const int x0i = (int)x0, y0i = (int)y0;
            auto pix = [&](int yi, int xi) -> float4 {
                const bool valid = (xi >= 0) & (xi < BW) & (yi >= 0) & (yi < BH);
                const int yc = min(max(yi, 0), BH - 1);
                const int xc = min(max(xi, 0), BW - 1);
                float4 v = *(const float4*)(xb + ((size_t)yc * BW + xc) * NC + c4);
                const float f = valid ? 1.f : 0.f;
                v.x *= f; v.y *= f; v.z *= f; v.w *= f;
                return v;
            };
            const float4 v00 = pix(y0i, x0i);
            const float4 v01 = pix(y0i, x0i + 1);
            const float4 v10 = pix(y0i + 1, x0i);
            const float4 v11 = pix(y0i + 1, x0i + 1);
            const float owx = 1.f - wxf, owy = 1.f - wyf;
            nfloat4 r;
            r.x = (v00.x * owx + v01.x * wxf) * owy + (v10.x * owx + v11.x * wxf) * wyf;
            r.y = (v00.y * owx + v01.y * wxf) * owy + (v10.y * owx + v11.y * wxf) * wyf;
            r.z = (v00.z * owx + v01.z * wxf) * owy + (v10.z * owx + v11.z * wxf) * wyf;
            r.w = (v00.w * owx + v01.w * wxf) * owy + (v10.w * owx + v11.w * wxf) * wyf;
            __builtin_nontemporal_store(r, (nfloat4*)(ob + (size_t)j * 4));
        }
    };

    for (int b = 0; b < NB; ++b) {
        // 1) issue cold reduce loads for batch b early
        const float4* xb4 = (const float4*)(x + (size_t)b * (BH * BW * NC));
        const int base = k * 512 + t;
        const float4 a0 = xb4[base];
        const float4 a1 = xb4[base + 256];
        // 2) rotate batch b-2 while those loads fly
        if (b >= 2) rotate_share(b - 2);
        // 3) finish reduce of batch b
        float s = a0.x * w0 + a0.y * w1 + a0.z * w2 + a0.w * w3
                + a1.x * w0 + a1.y * w1 + a1.z * w2 + a1.w * w3;
        #pragma unroll
        for (int off = 32; off; off >>= 1) s += __shfl_down(s, off, 64);
        if (lane == 0) red[b & 1][wv] = s;
        __syncthreads();
        // 4) wave0 bookkeeping; waves 1-3 run ahead (they write red[(b+1)&1],
        //    and cannot pass iteration b+1's barrier before wave0 gets here)
        if (wv == 0) {
            int last = 0;
            if (lane == 0) {
                const float bsum = red[b & 1][0] + red[b & 1][1]
                                 + red[b & 1][2] + red[b & 1][3];
                __hip_atomic_store(&partial[b * NBLK + k], bsum, __ATOMIC_RELAXED, AGENT);
                const unsigned old =
                    __hip_atomic_fetch_add(&cnt[b], 1u, __ATOMIC_ACQ_REL, AGENT);
                last = (old == NBLK - 1);
            }
            last = __shfl(last, 0, 64);
            if (last) {   // this wave finalizes batch b (fixed order -> deterministic)
                __builtin_amdgcn_fence(__ATOMIC_ACQUIRE, "agent");
                const float* pb = partial + b * NBLK;
                float q = 0.f;
                #pragma unroll
                for (int i = 0; i < 16; ++i) q += pb[lane + 64 * i];
                #pragma unroll
                for (int off = 32; off; off >>= 1) q += __shfl_down(q, off, 64);
                if (lane == 0) {
                    const float pi = 3.14159265358979323846f;
                    float angle = tanhf(q * (1.f / (BH * BW)) + bias0) * pi;
                    angle = fminf(fmaxf(angle, -pi), pi);
                    const float c_ = cosf(angle), s_ = sinf(angle);
                    const float w1f = (float)(BW - 1), h1f = (float)(BH - 1);
                    params[b * 4 + 0] = c_;
                    params[b * 4 + 1] = s_;
                    params[b * 4 + 2] = (w1f - (c_ * w1f - s_ * h1f)) * 0.5f;
                    params[b * 4 + 3] = (h1f - (s_ * w1f + c_ * h1f)) * 0.5f;
                    __hip_atomic_store(&ready[b], 1u, __ATOMIC_RELEASE, AGENT);
                }
            }
        }
    }
    rotate_share(NB - 2);
    rotate_share(NB - 1);
}

// ============================ fallback (R3/R7 proven path) ===================
__global__ __launch_bounds__(256) void k_reduce(const float* __restrict__ x,
                                                const float* __restrict__ Wm,
                                                float* __restrict__ partial) {
    const int b = blockIdx.y, blk = blockIdx.x;
    const int tid = blk * 256 + threadIdx.x;
    const int tpb = RB * 256;
    const int cb = (tid * 4) & (NC - 1);
    const float w0 = Wm[cb], w1 = Wm[cb + 1], w2 = Wm[cb + 2], w3 = Wm[cb + 3];
    const float4* xb = (const float4*)(x + (size_t)b * BH * BW * NC);
    const int n4 = BH * BW * NC / 4;
    float s0 = 0.f, s1 = 0.f;
    for (int i = tid; i < n4; i += 2 * tpb) {
        float4 v0 = xb[i], v1 = xb[i + tpb];
        s0 += v0.x * w0 + v0.y * w1 + v0.z * w2 + v0.w * w3;
        s1 += v1.x * w0 + v1.y * w1 + v1.z * w2 + v1.w * w3;
    }
    float s = s0 + s1;
    for (int off = 32; off; off >>= 1) s += __shfl_down(s, off, 64);
    __shared__ float red[4];
    const int lane = threadIdx.x & 63, wv = threadIdx.x >> 6;
    if (lane == 0) red[wv] = s;
    __syncthreads();
    if (threadIdx.x == 0) partial[b * RB + blk] = red[0] + red[1] + red[2] + red[3];
}

__global__ void k_angle(const float* __restrict__ partial,
                        const float* __restrict__ bias,
                        float4* __restrict__ params) {
    const int b = threadIdx.x;
    if (b >= NB) return;
    float s = 0.f;
    for (int i = 0; i < RB; ++i) s += partial[b * RB + i];
    const float pi = 3.14159265358979323846f;
    float angle = tanhf(s * (1.f / (BH * BW)) + bias[0]) * pi;
    angle = fminf(fmaxf(angle, -pi), pi);
    const float cc = cosf(angle), ss = sinf(angle);
    const float w1 = (float)(BW - 1), h1 = (float)(BH - 1);
    params[b] = make_float4(cc, ss, (w1 - (cc * w1 - ss * h1)) * 0.5f,
                            (h1 - (ss * w1 + cc * h1)) * 0.5f);
}

__global__ __launch_bounds__(256) void k_rotate(const float* __restrict__ x,
                                                const float4* __restrict__ params,
                                                float* __restrict__ out) {
    const int gid = blockIdx.x * 256 + threadIdx.x;
    const int c4 = (gid & 7) * 4;
    const int pid = gid >> 3;
    const int b = pid >> 16, p = pid & 65535;
    const int yo = p >> 8, xo = p & 255;
    const float4 prm = params[b];
    const float cc = prm.x, sn = prm.y, xof = prm.z, yof = prm.w;
    const float fx = (float)xo, fy = (float)yo;
    const float in_x = cc * fx - sn * fy + xof;
    const float in_y = sn * fx + cc * fy + yof;
    const float x0 = floorf(in_x), y0 = floorf(in_y);
    const float wxf = in_x - x0, wyf = in_y - y0;
    const int x0i = (int)x0, y0i = (int)y0;
    const float* xb = x + (size_t)b * (BH * BW * NC);
    auto pix = [&](int yi, int xi) -> float4 {
        const bool valid = (xi >= 0) & (xi < BW) & (yi >= 0) & (yi < BH);
        const int yc = min(max(yi, 0), BH - 1), xc = min(max(xi, 0), BW - 1);
        float4 v = *(const float4*)(xb + ((size_t)yc * BW + xc) * NC + c4);
        const float f = valid ? 1.f : 0.f;
        v.x *= f; v.y *= f; v.z *= f; v.w *= f;
        return v;
    };
    const float4 v00 = pix(y0i, x0i), v01 = pix(y0i, x0i + 1);
    const float4 v10 = pix(y0i + 1, x0i), v11 = pix(y0i + 1, x0i + 1);
    const float owx = 1.f - wxf, owy = 1.f - wyf;
    nfloat4 r;
    r.x = (v00.x * owx + v01.x * wxf) * owy + (v10.x * owx + v11.x * wxf) * wyf;
    r.y = (v00.y * owx + v01.y * wxf) * owy + (v10.y * owx + v11.y * wxf) * wyf;
    r.z = (v00.z * owx + v01.z * wxf) * owy + (v10.z * owx + v11.z * wxf) * wyf;
    r.w = (v00.w * owx + v01.w * wxf) * owy + (v10.w * owx + v11.w * wxf) * wyf;
    __builtin_nontemporal_store(r, (nfloat4*)(out + (size_t)gid * 4));
}

static void launch_fallback(const float* x, const float* Wm, const float* bias,
                            float* out, char* ws, hipStream_t stream) {
    float*  partial = (float*)ws;
    float4* params  = (float4*)(ws + NB * RB * sizeof(float));
    dim3 g1(RB, NB);
    k_reduce<<<g1, 256, 0, stream>>>(x, Wm, partial);
    k_angle<<<1, 64, 0, stream>>>(partial, bias, params);
    k_rotate<<<NB * BH * BW * NC / 4 / 256, 256, 0, stream>>>(x, params, out);
}

// ================================ launcher ==================================
extern "C" void kernel_launch(void* const* d_in, const int* in_sizes, int n_in,
                              void* d_out, int out_size, void* d_ws, size_t ws_size,
                              hipStream_t stream) {
    const float* x    = (const float*)d_in[0];
    const float* Wm   = (const float*)d_in[1];
    const float* bias = (const float*)d_in[2];
    float* out = (float*)d_out;
    char* ws = (char*)d_ws;

    const size_t PART_BYTES = (size_t)NB * NBLK * sizeof(float);  // 128 KiB
    if (ws_size >= PART_BYTES + 1024) {
        float*    partial = (float*)ws;
        unsigned* cnt     = (unsigned*)(ws + PART_BYTES);          // 128 B
        unsigned* ready   = (unsigned*)(ws + PART_BYTES + 128);    // 128 B
        float*    params  = (float*)(ws + PART_BYTES + 256);       // 512 B
        if (hipMemsetAsync(ws + PART_BYTES, 0, 256, stream) == hipSuccess) {
            void* args[] = { (void*)&x, (void*)&Wm, (void*)&bias, (void*)&out,
                             (void*)&partial, (void*)&cnt, (void*)&ready,
                             (void*)&params };
            hipError_t err = hipLaunchCooperativeKernel((const void*)k_fused,
                                                        dim3(NBLK), dim3(TPB),
                                                        args, 0, stream);
            if (err == hipSuccess) return;          // fused path launched
        }
    }
    launch_fallback(x, Wm, bias, out, ws, stream);  // proven 130 µs path
}

// Round 9
// 444.369 us; speedup vs baseline: 10.8941x; 10.8941x over previous
//
#include <hip/hip_runtime.h>
#include <math.h>

#define BH 256
#define BW 256
#define NB 32
#define NC 32
#define NBLK 1024   // fused-path blocks (4/CU at 256 thr, coop-launch guaranteed resident)
#define TPB 256
#define G 4         // batches per pipeline stage
#define NG (NB / G) // 8 stages
#define RB 64       // fallback-path reduction blocks per batch

typedef float nfloat4 __attribute__((ext_vector_type(4)));
#define AGENT __HIP_MEMORY_SCOPE_AGENT

// ============================ fused pipelined kernel =========================
// Stage g: reduce slices of batches [g*G, g*G+4); rotate batches of stage g-2.
// ALL cross-block sync data moves through agent-scope RELAXED atomics (executed
// at L3, the coherence point) -- no acquire fences, no L1/L2 invalidations, so
// x stays L2/L3-resident for the rotate re-read. RELEASE only on arrival
// fetch_add and ready publish (vmcnt drain, no cache inv). Two-level arrival
// tree caps same-address atomic contention at 32. Only wave0/lane0 polls.
__global__ __launch_bounds__(TPB, 4) void k_fused(
    const float* __restrict__ x, const float* __restrict__ Wm,
    const float* __restrict__ bias, float* __restrict__ out,
    float* __restrict__ partial,          // [NB][NBLK]
    unsigned* __restrict__ cnt1,          // [NG][32]
    unsigned* __restrict__ cnt2,          // [NG]
    unsigned* __restrict__ ready,         // [NG]
    float* __restrict__ params)           // [NB][4] = cc, sn, xoff, yoff
{
    const int k = blockIdx.x, t = threadIdx.x;
    const int lane = t & 63, wv = t >> 6;
    __shared__ float red[2][G][4];        // parity-buffered reduce scratch
    __shared__ float sprm[G * 4];

    const int cb = (t * 4) & (NC - 1);    // k*512*4 % 32 == 0 -> depends on t only
    const float w0 = Wm[cb], w1 = Wm[cb + 1], w2 = Wm[cb + 2], w3 = Wm[cb + 3];
    const float bias0 = bias[0];

    auto rotate_group = [&](int g) {
        if (wv == 0) {
            if (lane == 0)
                while (__hip_atomic_load(&ready[g], __ATOMIC_RELAXED, AGENT) == 0u)
                    __builtin_amdgcn_s_sleep(8);
            if (lane < G * 4)
                sprm[lane] = __hip_atomic_load(&params[g * G * 4 + lane],
                                               __ATOMIC_RELAXED, AGENT);
        }
        __syncthreads();
        #pragma unroll
        for (int u = 0; u < G; ++u) {
            const int bb = g * G + u;
            const float cc = sprm[u * 4 + 0], sn = sprm[u * 4 + 1];
            const float xof = sprm[u * 4 + 2], yof = sprm[u * 4 + 3];
            const float* xb = x + (size_t)bb * (BH * BW * NC);
            float* ob = out + (size_t)bb * (BH * BW * NC);
            #pragma unroll
            for (int h = 0; h < 2; ++h) {
                const int j   = k * 512 + h * 256 + t;   // float4 index in batch
                const int c4  = (j & 7) * 4;
                const int pid = j >> 3;
                const int xo = pid & 255, yo = pid >> 8;
                const float fx = (float)xo, fy = (float)yo;
                const float in_x = cc * fx - sn * fy + xof;
                const float in_y = sn * fx + cc * fy + yof;
                const float x0 = floorf(in_x), y0 = floorf(in_y);
                const float wxf = in_x - x0, wyf = in_y - y0;
                const int x0i = (int)x0, y0i = (int)y0;
                auto pix = [&](int yi, int xi) -> float4 {
                    const bool valid = (xi >= 0) & (xi < BW) & (yi >= 0) & (yi < BH);
                    const int yc = min(max(yi, 0), BH - 1);
                    const int xc = min(max(xi, 0), BW - 1);
                    float4 v = *(const float4*)(xb + ((size_t)yc * BW + xc) * NC + c4);
                    const float f = valid ? 1.f : 0.f;
                    v.x *= f; v.y *= f; v.z *= f; v.w *= f;
                    return v;
                };
                const float4 v00 = pix(y0i, x0i);
                const float4 v01 = pix(y0i, x0i + 1);
                const float4 v10 = pix(y0i + 1, x0i);
                const float4 v11 = pix(y0i + 1, x0i + 1);
                const float owx = 1.f - wxf, owy = 1.f - wyf;
                nfloat4 r;
                r.x = (v00.x * owx + v01.x * wxf) * owy + (v10.x * owx + v11.x * wxf) * wyf;
                r.y = (v00.y * owx + v01.y * wxf) * owy + (v10.y * owx + v11.y * wxf) * wyf;
                r.z = (v00.z * owx + v01.z * wxf) * owy + (v10.z * owx + v11.z * wxf) * wyf;
                r.w = (v00.w * owx + v01.w * wxf) * owy + (v10.w * owx + v11.w * wxf) * wyf;
                __builtin_nontemporal_store(r, (nfloat4*)(ob + (size_t)j * 4));
            }
        }
    };

    for (int g = 0; g < NG; ++g) {
        // 1) issue cold reduce loads for stage g (fly under the poll/rotate)
        float4 a[G][2];
        const int base = k * 512 + t;
        #pragma unroll
        for (int u = 0; u < G; ++u) {
            const float4* xb4 = (const float4*)(x + (size_t)(g * G + u) * (BH * BW * NC));
            a[u][0] = xb4[base];
            a[u][1] = xb4[base + 256];
        }
        // 2) rotate stage g-2 while those loads fly
        if (g >= 2) rotate_group(g - 2);
        // 3) finish reduce of stage g
        float s[G];
        #pragma unroll
        for (int u = 0; u < G; ++u) {
            s[u] = a[u][0].x * w0 + a[u][0].y * w1 + a[u][0].z * w2 + a[u][0].w * w3
                 + a[u][1].x * w0 + a[u][1].y * w1 + a[u][1].z * w2 + a[u][1].w * w3;
            #pragma unroll
            for (int off = 32; off; off >>= 1) s[u] += __shfl_down(s[u], off, 64);
        }
        if (lane == 0) {
            #pragma unroll
            for (int u = 0; u < G; ++u) red[g & 1][u][wv] = s[u];
        }
        __syncthreads();
        // 4) wave0 bookkeeping; waves 1-3 run ahead (parity-buffered red)
        if (wv == 0) {
            if (lane < G) {
                const float* r = red[g & 1][lane];
                const float bsum = r[0] + r[1] + r[2] + r[3];
                __hip_atomic_store(&partial[(size_t)(g * G + lane) * NBLK + k], bsum,
                                   __ATOMIC_RELAXED, AGENT);
            }
            int last = 0;
            if (lane == 0) {
                // RELEASE: vmcnt-drains this wave's partial stores to L3 first
                const unsigned o1 = __hip_atomic_fetch_add(&cnt1[g * 32 + (k >> 5)],
                                                           1u, __ATOMIC_RELEASE, AGENT);
                if (o1 == 31u) {
                    const unsigned o2 = __hip_atomic_fetch_add(&cnt2[g], 1u,
                                                               __ATOMIC_RELEASE, AGENT);
                    last = (o2 == 31u);
                }
            }
            last = __shfl(last, 0, 64);
            if (last) {   // this wave finalizes stage g (fixed order -> deterministic)
                float q[G] = {0.f, 0.f, 0.f, 0.f};
                #pragma unroll
                for (int u = 0; u < G; ++u) {
                    const float* pb = partial + (size_t)(g * G + u) * NBLK;
                    #pragma unroll
                    for (int i = 0; i < 16; ++i)
                        q[u] += __hip_atomic_load(&pb[lane + 64 * i],
                                                  __ATOMIC_RELAXED, AGENT);
                }
                #pragma unroll
                for (int u = 0; u < G; ++u) {
                    #pragma unroll
                    for (int off = 32; off; off >>= 1)
                        q[u] += __shfl_down(q[u], off, 64);
                }
                float myq = 0.f;
                #pragma unroll
                for (int u = 0; u < G; ++u) {
                    const float tq = __shfl(q[u], 0, 64);
                    if (lane == u) myq = tq;
                }
                if (lane < G) {
                    const float pi = 3.14159265358979323846f;
                    float angle = tanhf(myq * (1.f / (BH * BW)) + bias0) * pi;
                    angle = fminf(fmaxf(angle, -pi), pi);
                    const float c_ = cosf(angle), s_ = sinf(angle);
                    const float w1f = (float)(BW - 1), h1f = (float)(BH - 1);
                    const int p4 = (g * G + lane) * 4;
                    __hip_atomic_store(&params[p4 + 0], c_, __ATOMIC_RELAXED, AGENT);
                    __hip_atomic_store(&params[p4 + 1], s_, __ATOMIC_RELAXED, AGENT);
                    __hip_atomic_store(&params[p4 + 2],
                                       (w1f - (c_ * w1f - s_ * h1f)) * 0.5f,
                                       __ATOMIC_RELAXED, AGENT);
                    __hip_atomic_store(&params[p4 + 3],
                                       (h1f - (s_ * w1f + c_ * h1f)) * 0.5f,
                                       __ATOMIC_RELAXED, AGENT);
                }
                if (lane == 0)  // RELEASE: drains the param stores first
                    __hip_atomic_store(&ready[g], 1u, __ATOMIC_RELEASE, AGENT);
            }
        }
    }
    rotate_group(NG - 2);
    rotate_group(NG - 1);
}

// ============================ fallback (R7 proven path) ======================
__global__ __launch_bounds__(256) void k_reduce(const float* __restrict__ x,
                                                const float* __restrict__ Wm,
                                                float* __restrict__ partial) {
    const int b = blockIdx.y, blk = blockIdx.x;
    const int tid = blk * 256 + threadIdx.x;
    const int tpb = RB * 256;
    const int cb = (tid * 4) & (NC - 1);
    const float w0 = Wm[cb], w1 = Wm[cb + 1], w2 = Wm[cb + 2], w3 = Wm[cb + 3];
    const float4* xb = (const float4*)(x + (size_t)b * BH * BW * NC);
    const int n4 = BH * BW * NC / 4;
    float s0 = 0.f, s1 = 0.f;
    for (int i = tid; i < n4; i += 2 * tpb) {
        float4 v0 = xb[i], v1 = xb[i + tpb];
        s0 += v0.x * w0 + v0.y * w1 + v0.z * w2 + v0.w * w3;
        s1 += v1.x * w0 + v1.y * w1 + v1.z * w2 + v1.w * w3;
    }
    float s = s0 + s1;
    for (int off = 32; off; off >>= 1) s += __shfl_down(s, off, 64);
    __shared__ float red[4];
    const int lane = threadIdx.x & 63, wv = threadIdx.x >> 6;
    if (lane == 0) red[wv] = s;
    __syncthreads();
    if (threadIdx.x == 0) partial[b * RB + blk] = red[0] + red[1] + red[2] + red[3];
}

__global__ void k_angle(const float* __restrict__ partial,
                        const float* __restrict__ bias,
                        float4* __restrict__ params) {
    const int b = threadIdx.x;
    if (b >= NB) return;
    float s = 0.f;
    for (int i = 0; i < RB; ++i) s += partial[b * RB + i];
    const float pi = 3.14159265358979323846f;
    float angle = tanhf(s * (1.f / (BH * BW)) + bias[0]) * pi;
    angle = fminf(fmaxf(angle, -pi), pi);
    const float cc = cosf(angle), ss = sinf(angle);
    const float w1 = (float)(BW - 1), h1 = (float)(BH - 1);
    params[b] = make_float4(cc, ss, (w1 - (cc * w1 - ss * h1)) * 0.5f,
                            (h1 - (ss * w1 + cc * h1)) * 0.5f);
}

__global__ __launch_bounds__(256) void k_rotate(const float* __restrict__ x,
                                                const float4* __restrict__ params,
                                                float* __restrict__ out) {
    const int gid = blockIdx.x * 256 + threadIdx.x;
    const int c4 = (gid & 7) * 4;
    const int pid = gid >> 3;
    const int b = pid >> 16, p = pid & 65535;
    const int yo = p >> 8, xo = p & 255;
    const float4 prm = params[b];
    const float cc = prm.x, sn = prm.y, xof = prm.z, yof = prm.w;
    const float fx = (float)xo, fy = (float)yo;
    const float in_x = cc * fx - sn * fy + xof;
    const float in_y = sn * fx + cc * fy + yof;
    const float x0 = floorf(in_x), y0 = floorf(in_y);
    const float wxf = in_x - x0, wyf = in_y - y0;
    const int x0i = (int)x0, y0i = (int)y0;
    const float* xb = x + (size_t)b * (BH * BW * NC);
    auto pix = [&](int yi, int xi) -> float4 {
        const bool valid = (xi >= 0) & (xi < BW) & (yi >= 0) & (yi < BH);
        const int yc = min(max(yi, 0), BH - 1), xc = min(max(xi, 0), BW - 1);
        float4 v = *(const float4*)(xb + ((size_t)yc * BW + xc) * NC + c4);
        const float f = valid ? 1.f : 0.f;
        v.x *= f; v.y *= f; v.z *= f; v.w *= f;
        return v;
    };
    const float4 v00 = pix(y0i, x0i), v01 = pix(y0i, x0i + 1);
    const float4 v10 = pix(y0i + 1, x0i), v11 = pix(y0i + 1, x0i + 1);
    const float owx = 1.f - wxf, owy = 1.f - wyf;
    nfloat4 r;
    r.x = (v00.x * owx + v01.x * wxf) * owy + (v10.x * owx + v11.x * wxf) * wyf;
    r.y = (v00.y * owx + v01.y * wxf) * owy + (v10.y * owx + v11.y * wxf) * wyf;
    r.z = (v00.z * owx + v01.z * wxf) * owy + (v10.z * owx + v11.z * wxf) * wyf;
    r.w = (v00.w * owx + v01.w * wxf) * owy + (v10.w * owx + v11.w * wxf) * wyf;
    __builtin_nontemporal_store(r, (nfloat4*)(out + (size_t)gid * 4));
}

static void launch_fallback(const float* x, const float* Wm, const float* bias,
                            float* out, char* ws, hipStream_t stream) {
    float*  partial = (float*)ws;
    float4* params  = (float4*)(ws + NB * RB * sizeof(float));
    dim3 g1(RB, NB);
    k_reduce<<<g1, 256, 0, stream>>>(x, Wm, partial);
    k_angle<<<1, 64, 0, stream>>>(partial, bias, params);
    k_rotate<<<NB * BH * BW * NC / 4 / 256, 256, 0, stream>>>(x, params, out);
}

// ================================ launcher ==================================
extern "C" void kernel_launch(void* const* d_in, const int* in_sizes, int n_in,
                              void* d_out, int out_size, void* d_ws, size_t ws_size,
                              hipStream_t stream) {
    const float* x    = (const float*)d_in[0];
    const float* Wm   = (const float*)d_in[1];
    const float* bias = (const float*)d_in[2];
    float* out = (float*)d_out;
    char* ws = (char*)d_ws;

    const size_t PART_BYTES = (size_t)NB * NBLK * sizeof(float);  // 128 KiB
    const size_t CTRL_BYTES = 1024 + 128 + 128;                   // cnt1+cnt2+ready
    if (ws_size >= PART_BYTES + CTRL_BYTES + 1024) {
        float*    partial = (float*)ws;
        unsigned* cnt1    = (unsigned*)(ws + PART_BYTES);               // 1 KiB
        unsigned* cnt2    = (unsigned*)(ws + PART_BYTES + 1024);        // 128 B
        unsigned* ready   = (unsigned*)(ws + PART_BYTES + 1024 + 128);  // 128 B
        float*    params  = (float*)(ws + PART_BYTES + CTRL_BYTES);     // 512 B
        if (hipMemsetAsync(ws + PART_BYTES, 0, CTRL_BYTES, stream) == hipSuccess) {
            void* args[] = { (void*)&x, (void*)&Wm, (void*)&bias, (void*)&out,
                             (void*)&partial, (void*)&cnt1, (void*)&cnt2,
                             (void*)&ready, (void*)&params };
            hipError_t err = hipLaunchCooperativeKernel((const void*)k_fused,
                                                        dim3(NBLK), dim3(TPB),
                                                        args, 0, stream);
            if (err == hipSuccess) return;          // fused path launched
        }
    }
    launch_fallback(x, Wm, bias, out, ws, stream);  // proven 130 µs path
}

// Round 10
// 201.635 us; speedup vs baseline: 24.0088x; 2.2038x over previous
//
#include <hip/hip_runtime.h>
#include <math.h>

#define BH 256
#define BW 256
#define NB 32
#define NC 32
#define NBLK 1024   // fused-path blocks (4/CU at 256 thr, coop-launch guaranteed resident)
#define TPB 256
#define G 4         // batches per pipeline stage
#define NG (NB / G) // 8 stages
#define RB 64       // fallback-path reduction blocks per batch

typedef float nfloat4 __attribute__((ext_vector_type(4)));
#define AGENT __HIP_MEMORY_SCOPE_AGENT

// ============================ fused pipelined kernel =========================
// Stage g: reduce slices of batches [g*G, g*G+G); rotate batches of stage g-2.
// NO acquire/release anywhere (agent release on gfx950 = L2 writeback storm:
// R8=5100us, R9=613us were sync-poisoned). Every cross-block datum is an
// agent-scope RELAXED atomic (executes at L3, the coherence point); ordering
// is by COMPLETION: store -> s_waitcnt vmcnt(0) -> flag/counter bump.
// Two-level arrival tree caps same-address contention at 32. Only wave0/lane0
// polls, with s_sleep backoff. Bookkeeping runs BEFORE the rotate phase so the
// publish is early and its vmcnt drain excludes this stage's NT stores.
__global__ __launch_bounds__(TPB, 4) void k_fused(
    const float* __restrict__ x, const float* __restrict__ Wm,
    const float* __restrict__ bias, float* __restrict__ out,
    float* __restrict__ partial,          // [NB][NBLK]
    unsigned* __restrict__ cnt1,          // [NG][32]
    unsigned* __restrict__ cnt2,          // [NG]
    unsigned* __restrict__ ready,         // [NG]
    float* __restrict__ params)           // [NB][4] = cc, sn, xoff, yoff
{
    const int k = blockIdx.x, t = threadIdx.x;
    const int lane = t & 63, wv = t >> 6;
    __shared__ float red[2][G][4];        // parity-buffered reduce scratch
    __shared__ float sprm[G * 4];

    const int cb = (t * 4) & (NC - 1);    // k*512*4 % 32 == 0 -> depends on t only
    const float w0 = Wm[cb], w1 = Wm[cb + 1], w2 = Wm[cb + 2], w3 = Wm[cb + 3];
    const float bias0 = bias[0];

    auto rotate_group = [&](int g) {
        if (wv == 0) {
            if (lane == 0)
                while (__hip_atomic_load(&ready[g], __ATOMIC_RELAXED, AGENT) == 0u)
                    __builtin_amdgcn_s_sleep(8);
            // wave-lockstep: these loads issue only after the poll loop exits
            if (lane < G * 4)
                sprm[lane] = __hip_atomic_load(&params[g * G * 4 + lane],
                                               __ATOMIC_RELAXED, AGENT);
        }
        __syncthreads();                  // B2: sprm valid; also fences sprm reuse
        #pragma unroll
        for (int u = 0; u < G; ++u) {
            const int bb = g * G + u;
            const float cc = sprm[u * 4 + 0], sn = sprm[u * 4 + 1];
            const float xof = sprm[u * 4 + 2], yof = sprm[u * 4 + 3];
            const float* xb = x + (size_t)bb * (BH * BW * NC);
            float* ob = out + (size_t)bb * (BH * BW * NC);
            #pragma unroll
            for (int h = 0; h < 2; ++h) {
                const int j   = k * 512 + h * 256 + t;   // float4 index in batch
                const int c4  = (j & 7) * 4;
                const int pid = j >> 3;
                const int xo = pid & 255, yo = pid >> 8;
                const float fx = (float)xo, fy = (float)yo;
                const float in_x = cc * fx - sn * fy + xof;
                const float in_y = sn * fx + cc * fy + yof;
                const float x0 = floorf(in_x), y0 = floorf(in_y);
                const float wxf = in_x - x0, wyf = in_y - y0;
                const int x0i = (int)x0, y0i = (int)y0;
                auto pix = [&](int yi, int xi) -> float4 {
                    const bool valid = (xi >= 0) & (xi < BW) & (yi >= 0) & (yi < BH);
                    const int yc = min(max(yi, 0), BH - 1);
                    const int xc = min(max(xi, 0), BW - 1);
                    float4 v = *(const float4*)(xb + ((size_t)yc * BW + xc) * NC + c4);
                    const float f = valid ? 1.f : 0.f;
                    v.x *= f; v.y *= f; v.z *= f; v.w *= f;
                    return v;
                };
                const float4 v00 = pix(y0i, x0i);
                const float4 v01 = pix(y0i, x0i + 1);
                const float4 v10 = pix(y0i + 1, x0i);
                const float4 v11 = pix(y0i + 1, x0i + 1);
                const float owx = 1.f - wxf, owy = 1.f - wyf;
                nfloat4 r;
                r.x = (v00.x * owx + v01.x * wxf) * owy + (v10.x * owx + v11.x * wxf) * wyf;
                r.y = (v00.y * owx + v01.y * wxf) * owy + (v10.y * owx + v11.y * wxf) * wyf;
                r.z = (v00.z * owx + v01.z * wxf) * owy + (v10.z * owx + v11.z * wxf) * wyf;
                r.w = (v00.w * owx + v01.w * wxf) * owy + (v10.w * owx + v11.w * wxf) * wyf;
                __builtin_nontemporal_store(r, (nfloat4*)(ob + (size_t)j * 4));
            }
        }
    };

    for (int g = 0; g < NG; ++g) {
        // 1) reduce loads for stage g (8 in flight; 16 waves/CU hide latency)
        float4 a[G][2];
        const int base = k * 512 + t;
        #pragma unroll
        for (int u = 0; u < G; ++u) {
            const float4* xb4 = (const float4*)(x + (size_t)(g * G + u) * (BH * BW * NC));
            a[u][0] = xb4[base];
            a[u][1] = xb4[base + 256];
        }
        // 2) reduce compute + wave reduce
        float s[G];
        #pragma unroll
        for (int u = 0; u < G; ++u) {
            s[u] = a[u][0].x * w0 + a[u][0].y * w1 + a[u][0].z * w2 + a[u][0].w * w3
                 + a[u][1].x * w0 + a[u][1].y * w1 + a[u][1].z * w2 + a[u][1].w * w3;
            #pragma unroll
            for (int off = 32; off; off >>= 1) s[u] += __shfl_down(s[u], off, 64);
        }
        if (lane == 0) {
            #pragma unroll
            for (int u = 0; u < G; ++u) red[g & 1][u][wv] = s[u];
        }
        __syncthreads();                  // B1
        // 3) wave0 bookkeeping FIRST (early publish; no NT stores outstanding
        //    from this stage yet). Ordering by completion, never by fence.
        if (wv == 0) {
            if (lane < G) {
                const float* r = red[g & 1][lane];
                const float bsum = r[0] + r[1] + r[2] + r[3];
                __hip_atomic_store(&partial[(size_t)(g * G + lane) * NBLK + k], bsum,
                                   __ATOMIC_RELAXED, AGENT);
            }
            asm volatile("s_waitcnt vmcnt(0)" ::: "memory");   // partials at L3
            int last = 0;
            if (lane == 0) {
                const unsigned o1 = __hip_atomic_fetch_add(&cnt1[g * 32 + (k >> 5)],
                                                           1u, __ATOMIC_RELAXED, AGENT);
                if (o1 == 31u) {
                    const unsigned o2 = __hip_atomic_fetch_add(&cnt2[g], 1u,
                                                               __ATOMIC_RELAXED, AGENT);
                    last = (o2 == 31u);
                }
            }
            last = __shfl(last, 0, 64);
            if (last) {   // finalize stage g (fixed order -> deterministic)
                float q[G] = {0.f, 0.f, 0.f, 0.f};
                #pragma unroll
                for (int u = 0; u < G; ++u) {
                    const float* pb = partial + (size_t)(g * G + u) * NBLK;
                    #pragma unroll
                    for (int i = 0; i < 16; ++i)
                        q[u] += __hip_atomic_load(&pb[lane + 64 * i],
                                                  __ATOMIC_RELAXED, AGENT);
                }
                #pragma unroll
                for (int u = 0; u < G; ++u) {
                    #pragma unroll
                    for (int off = 32; off; off >>= 1)
                        q[u] += __shfl_down(q[u], off, 64);
                }
                float myq = 0.f;
                #pragma unroll
                for (int u = 0; u < G; ++u) {
                    const float tq = __shfl(q[u], 0, 64);
                    if (lane == u) myq = tq;
                }
                if (lane < G) {
                    const float pi = 3.14159265358979323846f;
                    float angle = tanhf(myq * (1.f / (BH * BW)) + bias0) * pi;
                    angle = fminf(fmaxf(angle, -pi), pi);
                    const float c_ = cosf(angle), s_ = sinf(angle);
                    const float w1f = (float)(BW - 1), h1f = (float)(BH - 1);
                    const int p4 = (g * G + lane) * 4;
                    __hip_atomic_store(&params[p4 + 0], c_, __ATOMIC_RELAXED, AGENT);
                    __hip_atomic_store(&params[p4 + 1], s_, __ATOMIC_RELAXED, AGENT);
                    __hip_atomic_store(&params[p4 + 2],
                                       (w1f - (c_ * w1f - s_ * h1f)) * 0.5f,
                                       __ATOMIC_RELAXED, AGENT);
                    __hip_atomic_store(&params[p4 + 3],
                                       (h1f - (s_ * w1f + c_ * h1f)) * 0.5f,
                                       __ATOMIC_RELAXED, AGENT);
                }
                asm volatile("s_waitcnt vmcnt(0)" ::: "memory"); // params at L3
                if (lane == 0)
                    __hip_atomic_store(&ready[g], 1u, __ATOMIC_RELAXED, AGENT);
            }
        }
        // 4) rotate stage g-2 (sprm race vs next fill is fenced by B1(g+1))
        if (g >= 2) rotate_group(g - 2);
    }
    rotate_group(NG - 2);
    rotate_group(NG - 1);
}

// ============================ fallback (R7 proven path) ======================
__global__ __launch_bounds__(256) void k_reduce(const float* __restrict__ x,
                                                const float* __restrict__ Wm,
                                                float* __restrict__ partial) {
    const int b = blockIdx.y, blk = blockIdx.x;
    const int tid = blk * 256 + threadIdx.x;
    const int tpb = RB * 256;
    const int cb = (tid * 4) & (NC - 1);
    const float w0 = Wm[cb], w1 = Wm[cb + 1], w2 = Wm[cb + 2], w3 = Wm[cb + 3];
    const float4* xb = (const float4*)(x + (size_t)b * BH * BW * NC);
    const int n4 = BH * BW * NC / 4;
    float s0 = 0.f, s1 = 0.f;
    for (int i = tid; i < n4; i += 2 * tpb) {
        float4 v0 = xb[i], v1 = xb[i + tpb];
        s0 += v0.x * w0 + v0.y * w1 + v0.z * w2 + v0.w * w3;
        s1 += v1.x * w0 + v1.y * w1 + v1.z * w2 + v1.w * w3;
    }
    float s = s0 + s1;
    for (int off = 32; off; off >>= 1) s += __shfl_down(s, off, 64);
    __shared__ float red[4];
    const int lane = threadIdx.x & 63, wv = threadIdx.x >> 6;
    if (lane == 0) red[wv] = s;
    __syncthreads();
    if (threadIdx.x == 0) partial[b * RB + blk] = red[0] + red[1] + red[2] + red[3];
}

__global__ void k_angle(const float* __restrict__ partial,
                        const float* __restrict__ bias,
                        float4* __restrict__ params) {
    const int b = threadIdx.x;
    if (b >= NB) return;
    float s = 0.f;
    for (int i = 0; i < RB; ++i) s += partial[b * RB + i];
    const float pi = 3.14159265358979323846f;
    float angle = tanhf(s * (1.f / (BH * BW)) + bias[0]) * pi;
    angle = fminf(fmaxf(angle, -pi), pi);
    const float cc = cosf(angle), ss = sinf(angle);
    const float w1 = (float)(BW - 1), h1 = (float)(BH - 1);
    params[b] = make_float4(cc, ss, (w1 - (cc * w1 - ss * h1)) * 0.5f,
                            (h1 - (ss * w1 + cc * h1)) * 0.5f);
}

__global__ __launch_bounds__(256) void k_rotate(const float* __restrict__ x,
                                                const float4* __restrict__ params,
                                                float* __restrict__ out) {
    const int gid = blockIdx.x * 256 + threadIdx.x;
    const int c4 = (gid & 7) * 4;
    const int pid = gid >> 3;
    const int b = pid >> 16, p = pid & 65535;
    const int yo = p >> 8, xo = p & 255;
    const float4 prm = params[b];
    const float cc = prm.x, sn = prm.y, xof = prm.z, yof = prm.w;
    const float fx = (float)xo, fy = (float)yo;
    const float in_x = cc * fx - sn * fy + xof;
    const float in_y = sn * fx + cc * fy + yof;
    const float x0 = floorf(in_x), y0 = floorf(in_y);
    const float wxf = in_x - x0, wyf = in_y - y0;
    const int x0i = (int)x0, y0i = (int)y0;
    const float* xb = x + (size_t)b * (BH * BW * NC);
    auto pix = [&](int yi, int xi) -> float4 {
        const bool valid = (xi >= 0) & (xi < BW) & (yi >= 0) & (yi < BH);
        const int yc = min(max(yi, 0), BH - 1), xc = min(max(xi, 0), BW - 1);
        float4 v = *(const float4*)(xb + ((size_t)yc * BW + xc) * NC + c4);
        const float f = valid ? 1.f : 0.f;
        v.x *= f; v.y *= f; v.z *= f; v.w *= f;
        return v;
    };
    const float4 v00 = pix(y0i, x0i), v01 = pix(y0i, x0i + 1);
    const float4 v10 = pix(y0i + 1, x0i), v11 = pix(y0i + 1, x0i + 1);
    const float owx = 1.f - wxf, owy = 1.f - wyf;
    nfloat4 r;
    r.x = (v00.x * owx + v01.x * wxf) * owy + (v10.x * owx + v11.x * wxf) * wyf;
    r.y = (v00.y * owx + v01.y * wxf) * owy + (v10.y * owx + v11.y * wxf) * wyf;
    r.z = (v00.z * owx + v01.z * wxf) * owy + (v10.z * owx + v11.z * wxf) * wyf;
    r.w = (v00.w * owx + v01.w * wxf) * owy + (v10.w * owx + v11.w * wxf) * wyf;
    __builtin_nontemporal_store(r, (nfloat4*)(out + (size_t)gid * 4));
}

static void launch_fallback(const float* x, const float* Wm, const float* bias,
                            float* out, char* ws, hipStream_t stream) {
    float*  partial = (float*)ws;
    float4* params  = (float4*)(ws + NB * RB * sizeof(float));
    dim3 g1(RB, NB);
    k_reduce<<<g1, 256, 0, stream>>>(x, Wm, partial);
    k_angle<<<1, 64, 0, stream>>>(partial, bias, params);
    k_rotate<<<NB * BH * BW * NC / 4 / 256, 256, 0, stream>>>(x, params, out);
}

// ================================ launcher ==================================
extern "C" void kernel_launch(void* const* d_in, const int* in_sizes, int n_in,
                              void* d_out, int out_size, void* d_ws, size_t ws_size,
                              hipStream_t stream) {
    const float* x    = (const float*)d_in[0];
    const float* Wm   = (const float*)d_in[1];
    const float* bias = (const float*)d_in[2];
    float* out = (float*)d_out;
    char* ws = (char*)d_ws;

    const size_t PART_BYTES = (size_t)NB * NBLK * sizeof(float);  // 128 KiB
    const size_t CTRL_BYTES = 1024 + 128 + 128;                   // cnt1+cnt2+ready
    if (ws_size >= PART_BYTES + CTRL_BYTES + 1024) {
        float*    partial = (float*)ws;
        unsigned* cnt1    = (unsigned*)(ws + PART_BYTES);               // 1 KiB
        unsigned* cnt2    = (unsigned*)(ws + PART_BYTES + 1024);        // 128 B
        unsigned* ready   = (unsigned*)(ws + PART_BYTES + 1024 + 128);  // 128 B
        float*    params  = (float*)(ws + PART_BYTES + CTRL_BYTES);     // 512 B
        if (hipMemsetAsync(ws + PART_BYTES, 0, CTRL_BYTES, stream) == hipSuccess) {
            void* args[] = { (void*)&x, (void*)&Wm, (void*)&bias, (void*)&out,
                             (void*)&partial, (void*)&cnt1, (void*)&cnt2,
                             (void*)&ready, (void*)&params };
            hipError_t err = hipLaunchCooperativeKernel((const void*)k_fused,
                                                        dim3(NBLK), dim3(TPB),
                                                        args, 0, stream);
            if (err == hipSuccess) return;          // fused path launched
        }
    }
    launch_fallback(x, Wm, bias, out, ws, stream);  // proven 130 µs path
}